// Round 1
// baseline (1910.252 us; speedup 1.0000x reference)
//
#include <hip/hip_runtime.h>
#include <hip/hip_bf16.h>

typedef __hip_bfloat16 bf16;
typedef float f32x4 __attribute__((ext_vector_type(4)));
typedef short s16x8 __attribute__((ext_vector_type(8)));

#define S_LEN 1024
#define BATCH 2
#define TDIM 138
#define DMOD 1024
#define NHEAD 16
#define DHEAD 64
#define NLAYER 8
#define FDIM 2048
#define MROWS (S_LEN*BATCH)   // 2048

// ---------------- weight f32 -> bf16 convert (vectorized x4) ----------------
__global__ __launch_bounds__(256) void f2b4_kernel(const float4* __restrict__ in,
                                                   ushort4* __restrict__ out, int n4) {
  int i = blockIdx.x * 256 + threadIdx.x;
  if (i >= n4) return;
  float4 v = in[i];
  ushort4 o;
  o.x = __builtin_bit_cast(unsigned short, __float2bfloat16(v.x));
  o.y = __builtin_bit_cast(unsigned short, __float2bfloat16(v.y));
  o.z = __builtin_bit_cast(unsigned short, __float2bfloat16(v.z));
  o.w = __builtin_bit_cast(unsigned short, __float2bfloat16(v.w));
  out[i] = o;
}

// ---------------- Win transpose (D,TD) -> (TD,D), f32 ----------------
__global__ __launch_bounds__(256) void transpose_win(const float* __restrict__ Win,
                                                     float* __restrict__ WinT) {
  int i = blockIdx.x * 256 + threadIdx.x;
  if (i >= TDIM * DMOD) return;
  int t = i / DMOD, d = i % DMOD;
  WinT[i] = Win[d * TDIM + t];
}

// ---------------- embed: x = tokens @ Win^T + bin + pos ----------------
__global__ __launch_bounds__(256) void embed_kernel(const float* __restrict__ tokens,
    const float* __restrict__ WinT, const float* __restrict__ binp,
    const float* __restrict__ pos, float* __restrict__ xf, bf16* __restrict__ xb) {
  int m = blockIdx.x;               // s*BATCH + b
  int d = blockIdx.y * 256 + threadIdx.x;
  int s = m >> 1;
  __shared__ float tok[TDIM];
  if (threadIdx.x < TDIM) tok[threadIdx.x] = tokens[m * TDIM + threadIdx.x];
  __syncthreads();
  float acc = binp[d] + pos[s * DMOD + d];
  for (int t = 0; t < TDIM; t++) acc += tok[t] * WinT[t * DMOD + d];
  xf[(size_t)m * DMOD + d] = acc;
  xb[(size_t)m * DMOD + d] = __float2bfloat16(acc);
}

// ---------------- NT GEMM: C[m,n] = sum_k A[m,k]*W[n,k] + bias[n] ----------------
// LAYOUT 0: row-major (m,n). LAYOUT 1: heads layout [b][h][s][dh], m=s*B+b, n=h*64+dh.
template<int LAYOUT, bool RELU, bool WF32, bool WBF16>
__global__ __launch_bounds__(256) void gemm_nt(
    const bf16* __restrict__ A, const bf16* __restrict__ W,
    const float* __restrict__ bias, float* __restrict__ Cf, bf16* __restrict__ Cb,
    int M, int N, int K) {
  __shared__ bf16 As[64][40];  // pitch 40 bf16 = 80B -> 2-way bank alias only (free)
  __shared__ bf16 Bs[64][40];
  int bn = blockIdx.x * 64;
  int bm = blockIdx.y * 64;
  int tid = threadIdx.x;
  int lane = tid & 63;
  int w = tid >> 6;
  int wr = (w >> 1) * 32, wc = (w & 1) * 32;
  int lo = lane & 15, hi = lane >> 4;

  f32x4 acc[2][2] = {};
  int arow = tid >> 2, aseg = (tid & 3) * 8;
  const size_t aoff = (size_t)(bm + arow) * K + aseg;
  const size_t boff = (size_t)(bn + arow) * K + aseg;

  for (int k0 = 0; k0 < K; k0 += 32) {
    *(s16x8*)(&As[arow][aseg]) = *(const s16x8*)(A + aoff + k0);
    *(s16x8*)(&Bs[arow][aseg]) = *(const s16x8*)(W + boff + k0);
    __syncthreads();
    s16x8 a0 = *(const s16x8*)(&As[wr + lo][hi * 8]);
    s16x8 a1 = *(const s16x8*)(&As[wr + 16 + lo][hi * 8]);
    s16x8 b0 = *(const s16x8*)(&Bs[wc + lo][hi * 8]);
    s16x8 b1 = *(const s16x8*)(&Bs[wc + 16 + lo][hi * 8]);
    acc[0][0] = __builtin_amdgcn_mfma_f32_16x16x32_bf16(a0, b0, acc[0][0], 0, 0, 0);
    acc[0][1] = __builtin_amdgcn_mfma_f32_16x16x32_bf16(a0, b1, acc[0][1], 0, 0, 0);
    acc[1][0] = __builtin_amdgcn_mfma_f32_16x16x32_bf16(a1, b0, acc[1][0], 0, 0, 0);
    acc[1][1] = __builtin_amdgcn_mfma_f32_16x16x32_bf16(a1, b1, acc[1][1], 0, 0, 0);
    __syncthreads();
  }
  for (int i = 0; i < 2; i++)
    for (int j = 0; j < 2; j++)
      for (int r = 0; r < 4; r++) {
        int m = bm + wr + i * 16 + hi * 4 + r;
        int n = bn + wc + j * 16 + lo;
        float v = acc[i][j][r] + bias[n];
        if (RELU) v = fmaxf(v, 0.0f);
        size_t idx;
        if (LAYOUT == 0) {
          idx = (size_t)m * N + n;
        } else {
          int s = m >> 1, b = m & 1, h = n >> 6, dh = n & 63;
          idx = (((size_t)(b * NHEAD + h)) * S_LEN + s) * DHEAD + dh;
        }
        if constexpr (WF32) Cf[idx] = v;
        if constexpr (WBF16) Cb[idx] = __float2bfloat16(v);
      }
}

// ---------------- RoPE (or plain cast) f32 heads-layout -> bf16 ----------------
template<bool ROPE>
__global__ __launch_bounds__(256) void rope_kernel(const float* __restrict__ in,
                                                   bf16* __restrict__ out) {
  int idx = blockIdx.x * 256 + threadIdx.x;     // pair index over B*H*S*32
  if (idx >= BATCH * NHEAD * S_LEN * 32) return;
  int i = idx & 31;
  int bhs = idx >> 5;
  int s = bhs & (S_LEN - 1);
  size_t base = (size_t)bhs * DHEAD + 2 * i;
  float x0 = in[base], x1 = in[base + 1];
  if (ROPE) {
    float ex = (float)(2 * i) * (1.0f / (float)DHEAD);
    float freq = expf(-ex * 9.210340371976184f);  // 10000^(-2i/Dh)
    float sn, cs;
    sincosf((float)s * freq, &sn, &cs);
    float o0 = x0 * cs - x1 * sn;
    float o1 = x1 * cs + x0 * sn;
    out[base] = __float2bfloat16(o0);
    out[base + 1] = __float2bfloat16(o1);
  } else {
    out[base] = __float2bfloat16(x0);
    out[base + 1] = __float2bfloat16(x1);
  }
}

// ---------------- flash attention (causal), Q/K/V [B*H][S][64] bf16 ----------------
// O written to (s,b,D) layout bf16 for the Wo GEMM.
__global__ __launch_bounds__(256) void flash_attn(const bf16* __restrict__ Q,
    const bf16* __restrict__ K, const bf16* __restrict__ V, bf16* __restrict__ O) {
  __shared__ bf16 Ks[32][72];      // pitch 144B -> conflict-free-ish frag reads
  __shared__ bf16 Vt[64][40];      // V transposed [d][k], pitch 80B
  __shared__ bf16 Pb[4][16][40];   // per-wave P tile [q][k]

  int qt = blockIdx.x;     // 16 q-tiles of 64
  int bh = blockIdx.y;     // b*NHEAD + h
  int b = bh >> 4, h = bh & 15;
  int tid = threadIdx.x;
  int w = tid >> 6, lane = tid & 63;
  int lo = lane & 15, hi = lane >> 4;
  const size_t sbase = (size_t)bh * S_LEN * DHEAD;
  int q0 = qt * 64 + w * 16;

  s16x8 aqlo = *(const s16x8*)(Q + sbase + (size_t)(q0 + lo) * DHEAD + hi * 8);
  s16x8 aqhi = *(const s16x8*)(Q + sbase + (size_t)(q0 + lo) * DHEAD + 32 + hi * 8);

  f32x4 accO[4] = {};
  float mrow[4] = {-INFINITY, -INFINITY, -INFINITY, -INFINITY};
  float lrow[4] = {0.f, 0.f, 0.f, 0.f};

  int nkt = qt * 2 + 2;
  int krow = tid >> 3, seg = tid & 7;
  for (int kt = 0; kt < nkt; kt++) {
    int kc = kt * 32;
    __syncthreads();   // prev-iter LDS reads done
    s16x8 kv = *(const s16x8*)(K + sbase + (size_t)(kc + krow) * DHEAD + seg * 8);
    *(s16x8*)(&Ks[krow][seg * 8]) = kv;
    s16x8 vv = *(const s16x8*)(V + sbase + (size_t)(kc + krow) * DHEAD + seg * 8);
    for (int j = 0; j < 8; j++) Vt[seg * 8 + j][krow] = ((const bf16*)&vv)[j];
    __syncthreads();

    s16x8 bk0l = *(const s16x8*)(&Ks[lo][hi * 8]);
    s16x8 bk0h = *(const s16x8*)(&Ks[lo][32 + hi * 8]);
    s16x8 bk1l = *(const s16x8*)(&Ks[16 + lo][hi * 8]);
    s16x8 bk1h = *(const s16x8*)(&Ks[16 + lo][32 + hi * 8]);
    f32x4 sc0 = {}, sc1 = {};
    sc0 = __builtin_amdgcn_mfma_f32_16x16x32_bf16(aqlo, bk0l, sc0, 0, 0, 0);
    sc0 = __builtin_amdgcn_mfma_f32_16x16x32_bf16(aqhi, bk0h, sc0, 0, 0, 0);
    sc1 = __builtin_amdgcn_mfma_f32_16x16x32_bf16(aqlo, bk1l, sc1, 0, 0, 0);
    sc1 = __builtin_amdgcn_mfma_f32_16x16x32_bf16(aqhi, bk1h, sc1, 0, 0, 0);

    const float scale = 0.125f;   // 1/sqrt(64)
    float p0[4], p1[4];
    for (int r = 0; r < 4; r++) {
      int qrow = q0 + hi * 4 + r;
      float s0 = sc0[r] * scale;
      float s1 = sc1[r] * scale;
      if (kc + lo > qrow) s0 = -INFINITY;
      if (kc + 16 + lo > qrow) s1 = -INFINITY;
      float pm = fmaxf(s0, s1);
      for (int d = 1; d < 16; d <<= 1) pm = fmaxf(pm, __shfl_xor(pm, d));
      float mnew = fmaxf(mrow[r], pm);
      float fs = __expf(mrow[r] - mnew);
      float e0 = __expf(s0 - mnew);
      float e1 = __expf(s1 - mnew);
      float ps = e0 + e1;
      for (int d = 1; d < 16; d <<= 1) ps += __shfl_xor(ps, d);
      lrow[r] = lrow[r] * fs + ps;
      mrow[r] = mnew;
      for (int c = 0; c < 4; c++) accO[c][r] *= fs;
      p0[r] = e0; p1[r] = e1;
    }
    for (int r = 0; r < 4; r++) {
      Pb[w][hi * 4 + r][lo] = __float2bfloat16(p0[r]);
      Pb[w][hi * 4 + r][16 + lo] = __float2bfloat16(p1[r]);
    }
    __syncthreads();   // P visible (uniform loop count per block)
    s16x8 pA = *(const s16x8*)(&Pb[w][lo][hi * 8]);
    for (int c = 0; c < 4; c++) {
      s16x8 vB = *(const s16x8*)(&Vt[c * 16 + lo][hi * 8]);
      accO[c] = __builtin_amdgcn_mfma_f32_16x16x32_bf16(pA, vB, accO[c], 0, 0, 0);
    }
  }
  for (int c = 0; c < 4; c++)
    for (int r = 0; r < 4; r++) {
      int qrow = q0 + hi * 4 + r;
      float v = accO[c][r] / lrow[r];
      O[((size_t)(qrow * BATCH + b)) * DMOD + h * DHEAD + c * 16 + lo] = __float2bfloat16(v);
    }
}

// ---------------- LayerNorm(a + r) * g + be -> outf/outb ----------------
__global__ __launch_bounds__(256) void ln_kernel(const float* __restrict__ a,
    const float* __restrict__ r, const float* __restrict__ g,
    const float* __restrict__ be, float* __restrict__ outf, bf16* __restrict__ outb) {
  int m = blockIdx.x;
  int tid = threadIdx.x;
  float vals[4];
  float s1 = 0.f, s2 = 0.f;
  for (int j = 0; j < 4; j++) {
    int d = tid + j * 256;
    float v = a[(size_t)m * DMOD + d] + r[(size_t)m * DMOD + d];
    vals[j] = v; s1 += v; s2 += v * v;
  }
  __shared__ float red[8];
  for (int d = 1; d < 64; d <<= 1) { s1 += __shfl_xor(s1, d); s2 += __shfl_xor(s2, d); }
  int w = tid >> 6, lane = tid & 63;
  if (lane == 0) { red[w] = s1; red[4 + w] = s2; }
  __syncthreads();
  s1 = red[0] + red[1] + red[2] + red[3];
  s2 = red[4] + red[5] + red[6] + red[7];
  float mean = s1 * (1.0f / DMOD);
  float var = s2 * (1.0f / DMOD) - mean * mean;
  float rstd = rsqrtf(var + 1e-5f);
  for (int j = 0; j < 4; j++) {
    int d = tid + j * 256;
    float o = (vals[j] - mean) * rstd * g[d] + be[d];
    outf[(size_t)m * DMOD + d] = o;
    outb[(size_t)m * DMOD + d] = __float2bfloat16(o);
  }
}

// ---------------- head: out[m] = dot(x[m,:], Wh) + bh ----------------
__global__ __launch_bounds__(256) void head_kernel(const float* __restrict__ x,
    const float* __restrict__ Wh, const float* __restrict__ bh, float* __restrict__ out) {
  int m = blockIdx.x * 4 + (threadIdx.x >> 6);
  int lane = threadIdx.x & 63;
  float s = 0.f;
  for (int j = 0; j < 16; j++) {
    int d = lane + j * 64;
    s += x[(size_t)m * DMOD + d] * Wh[d];
  }
  for (int d = 1; d < 64; d <<= 1) s += __shfl_xor(s, d);
  if (lane == 0) out[m] = s + bh[0];
}

extern "C" void kernel_launch(void* const* d_in, const int* in_sizes, int n_in,
                              void* d_out, int out_size, void* d_ws, size_t ws_size,
                              hipStream_t stream) {
  (void)in_sizes; (void)n_in; (void)out_size; (void)ws_size;
  const float* tokens = (const float*)d_in[0];
  const float* Win    = (const float*)d_in[1];
  const float* binp   = (const float*)d_in[2];
  const float* pos    = (const float*)d_in[3];
  const float* Wq     = (const float*)d_in[4];
  const float* bq     = (const float*)d_in[5];
  const float* Wk     = (const float*)d_in[6];
  const float* bk     = (const float*)d_in[7];
  const float* Wv     = (const float*)d_in[8];
  const float* bv     = (const float*)d_in[9];
  const float* Wo     = (const float*)d_in[10];
  const float* bo     = (const float*)d_in[11];
  const float* W1     = (const float*)d_in[12];
  const float* b1     = (const float*)d_in[13];
  const float* W2     = (const float*)d_in[14];
  const float* b2     = (const float*)d_in[15];
  const float* g1     = (const float*)d_in[16];
  const float* be1    = (const float*)d_in[17];
  const float* g2     = (const float*)d_in[18];
  const float* be2    = (const float*)d_in[19];
  const float* Wh     = (const float*)d_in[20];
  const float* bhp    = (const float*)d_in[21];
  float* out = (float*)d_out;

  char* p = (char*)d_ws;
  auto alloc = [&](size_t bytes) { char* r = p; p += (bytes + 255) & ~(size_t)255; return r; };
  float* xf  = (float*)alloc((size_t)MROWS * DMOD * 4);
  bf16*  xb  = (bf16*) alloc((size_t)MROWS * DMOD * 2);
  float* x2f = (float*)alloc((size_t)MROWS * DMOD * 4);
  bf16*  x2b = (bf16*) alloc((size_t)MROWS * DMOD * 2);
  float* tmpf= (float*)alloc((size_t)MROWS * DMOD * 4);
  bf16*  qb  = (bf16*) alloc((size_t)MROWS * DMOD * 2);
  bf16*  kb  = (bf16*) alloc((size_t)MROWS * DMOD * 2);
  bf16*  vb  = (bf16*) alloc((size_t)MROWS * DMOD * 2);
  bf16*  ob  = (bf16*) alloc((size_t)MROWS * DMOD * 2);
  bf16*  hb  = (bf16*) alloc((size_t)MROWS * FDIM * 2);
  bf16*  wb  = (bf16*) alloc((size_t)FDIM * DMOD * 2);   // per-layer weight scratch
  float* WinT= (float*)alloc((size_t)TDIM * DMOD * 4);

  auto f2b = [&](const float* src, bf16* dst, size_t n) {
    int n4 = (int)(n / 4);
    f2b4_kernel<<<(n4 + 255) / 256, 256, 0, stream>>>((const float4*)src, (ushort4*)dst, n4);
  };

  transpose_win<<<(TDIM * DMOD + 255) / 256, 256, 0, stream>>>(Win, WinT);
  embed_kernel<<<dim3(MROWS, 4), 256, 0, stream>>>(tokens, WinT, binp, pos, xf, xb);

  const size_t DD = (size_t)DMOD * DMOD;
  const size_t FD = (size_t)FDIM * DMOD;
  const int ropeBlocks = (BATCH * NHEAD * S_LEN * 32 + 255) / 256;

  for (int l = 0; l < NLAYER; l++) {
    // Q
    f2b(Wq + l * DD, wb, DD);
    gemm_nt<1, false, true, false><<<dim3(DMOD / 64, MROWS / 64), 256, 0, stream>>>(
        xb, wb, bq + l * DMOD, tmpf, nullptr, MROWS, DMOD, DMOD);
    rope_kernel<true><<<ropeBlocks, 256, 0, stream>>>(tmpf, qb);
    // K
    f2b(Wk + l * DD, wb, DD);
    gemm_nt<1, false, true, false><<<dim3(DMOD / 64, MROWS / 64), 256, 0, stream>>>(
        xb, wb, bk + l * DMOD, tmpf, nullptr, MROWS, DMOD, DMOD);
    rope_kernel<true><<<ropeBlocks, 256, 0, stream>>>(tmpf, kb);
    // V
    f2b(Wv + l * DD, wb, DD);
    gemm_nt<1, false, true, false><<<dim3(DMOD / 64, MROWS / 64), 256, 0, stream>>>(
        xb, wb, bv + l * DMOD, tmpf, nullptr, MROWS, DMOD, DMOD);
    rope_kernel<false><<<ropeBlocks, 256, 0, stream>>>(tmpf, vb);
    // attention
    flash_attn<<<dim3(S_LEN / 64, BATCH * NHEAD), 256, 0, stream>>>(qb, kb, vb, ob);
    // Wo proj
    f2b(Wo + l * DD, wb, DD);
    gemm_nt<0, false, true, false><<<dim3(DMOD / 64, MROWS / 64), 256, 0, stream>>>(
        ob, wb, bo + l * DMOD, tmpf, nullptr, MROWS, DMOD, DMOD);
    ln_kernel<<<MROWS, 256, 0, stream>>>(xf, tmpf, g1 + l * DMOD, be1 + l * DMOD, x2f, x2b);
    // FFN
    f2b(W1 + l * FD, wb, FD);
    gemm_nt<0, true, false, true><<<dim3(FDIM / 64, MROWS / 64), 256, 0, stream>>>(
        x2b, wb, b1 + l * FDIM, nullptr, hb, MROWS, FDIM, DMOD);
    f2b(W2 + l * FD, wb, FD);
    gemm_nt<0, false, true, false><<<dim3(DMOD / 64, MROWS / 64), 256, 0, stream>>>(
        hb, wb, b2 + l * DMOD, tmpf, nullptr, MROWS, DMOD, FDIM);
    ln_kernel<<<MROWS, 256, 0, stream>>>(x2f, tmpf, g2 + l * DMOD, be2 + l * DMOD, xf, xb);
  }

  head_kernel<<<MROWS / 4, 256, 0, stream>>>(xf, Wh, bhp, out);
}

// Round 2
// 1681.413 us; speedup vs baseline: 1.1361x; 1.1361x over previous
//
#include <hip/hip_runtime.h>
#include <hip/hip_bf16.h>

typedef __hip_bfloat16 bf16;
typedef float f32x4 __attribute__((ext_vector_type(4)));
typedef short s16x8 __attribute__((ext_vector_type(8)));
typedef int i32x4 __attribute__((ext_vector_type(4)));

#define S_LEN 1024
#define BATCH 2
#define TDIM 138
#define DMOD 1024
#define NHEAD 16
#define DHEAD 64
#define NLAYER 8
#define FDIM 2048
#define MROWS 2048
static const size_t DD_ = (size_t)DMOD * DMOD;   // 1M elems
static const size_t FD_ = (size_t)FDIM * DMOD;   // 2M elems

__device__ __forceinline__ void load_lds16(const bf16* g, bf16* l) {
  __builtin_amdgcn_global_load_lds((const __attribute__((address_space(1))) void*)g,
                                   (__attribute__((address_space(3))) void*)l, 16, 0, 0);
}

__device__ __forceinline__ unsigned pack2(float a, float b) {
  unsigned x = __builtin_bit_cast(unsigned short, __float2bfloat16(a));
  unsigned y = __builtin_bit_cast(unsigned short, __float2bfloat16(b));
  return x | (y << 16);
}

// ---------------- per-layer weight f32 -> bf16 convert (one dispatch) ----------------
// wb layout: [0,3DD): Wq|Wk|Wv  [3DD,4DD): Wo  [4DD,4DD+FD): W1  [4DD+FD,4DD+2FD): W2
__global__ __launch_bounds__(256) void f2b_layer(
    const float4* __restrict__ Wq, const float4* __restrict__ Wk,
    const float4* __restrict__ Wv, const float4* __restrict__ Wo,
    const float4* __restrict__ W1, const float4* __restrict__ W2,
    ushort4* __restrict__ dst) {
  int i = blockIdx.x * 256 + threadIdx.x;
  const int DD4 = (int)(DD_ / 4), FD4 = (int)(FD_ / 4);
  if (i >= 4 * DD4 + 2 * FD4) return;
  const float4* src; int off;
  if (i < 3 * DD4) { int w = i / DD4; off = i - w * DD4; src = w == 0 ? Wq : (w == 1 ? Wk : Wv); }
  else if (i < 4 * DD4) { src = Wo; off = i - 3 * DD4; }
  else if (i < 4 * DD4 + FD4) { src = W1; off = i - 4 * DD4; }
  else { src = W2; off = i - 4 * DD4 - FD4; }
  float4 v = src[off];
  ushort4 o;
  o.x = __builtin_bit_cast(unsigned short, __float2bfloat16(v.x));
  o.y = __builtin_bit_cast(unsigned short, __float2bfloat16(v.y));
  o.z = __builtin_bit_cast(unsigned short, __float2bfloat16(v.z));
  o.w = __builtin_bit_cast(unsigned short, __float2bfloat16(v.w));
  dst[i] = o;
}

// ---------------- rope table: (cos, sin) per (s, i) ----------------
__global__ __launch_bounds__(256) void rope_table(float2* __restrict__ t) {
  int idx = blockIdx.x * 256 + threadIdx.x;
  if (idx >= S_LEN * 32) return;
  int s = idx >> 5, i = idx & 31;
  float freq = __expf(-(float)i * (2.0f / (float)DHEAD) * 9.210340371976184f);
  float sn, cs;
  sincosf((float)s * freq, &sn, &cs);
  t[idx] = make_float2(cs, sn);
}

// ---------------- Win transpose (D,TD) -> (TD,D), f32 ----------------
__global__ __launch_bounds__(256) void transpose_win(const float* __restrict__ Win,
                                                     float* __restrict__ WinT) {
  int i = blockIdx.x * 256 + threadIdx.x;
  if (i >= TDIM * DMOD) return;
  int t = i / DMOD, d = i % DMOD;
  WinT[i] = Win[d * TDIM + t];
}

// ---------------- embed: x = tokens @ Win^T + bin + pos ----------------
__global__ __launch_bounds__(256) void embed_kernel(const float* __restrict__ tokens,
    const float* __restrict__ WinT, const float* __restrict__ binp,
    const float* __restrict__ pos, float* __restrict__ xf, bf16* __restrict__ xb) {
  int m = blockIdx.x;
  int d = blockIdx.y * 256 + threadIdx.x;
  int s = m >> 1;
  __shared__ float tok[TDIM];
  if (threadIdx.x < TDIM) tok[threadIdx.x] = tokens[m * TDIM + threadIdx.x];
  __syncthreads();
  float acc = binp[d] + pos[s * DMOD + d];
  for (int t = 0; t < TDIM; t++) acc += tok[t] * WinT[t * DMOD + d];
  xf[(size_t)m * DMOD + d] = acc;
  xb[(size_t)m * DMOD + d] = __float2bfloat16(acc);
}

// ---------------- 128-tile NT GEMM (m97 structure: global_load_lds 16B) ----------------
// C[m,n] = sum_k A[m,k]*W[n,k] (+bias).  EPI 0: fused QKV (rope Q/K head-layout, V^T)
// EPI 1: f32 row-major. EPI 2: relu -> bf16 row-major.
template<int TN, int EPI>
__global__ __launch_bounds__(256) void gemm128(
    const bf16* __restrict__ A, const bf16* __restrict__ W,
    const float* __restrict__ b0p, const float* __restrict__ b1p, const float* __restrict__ b2p,
    const float2* __restrict__ rope2, float* __restrict__ Cf,
    bf16* __restrict__ Cb0, bf16* __restrict__ Cb1, bf16* __restrict__ Cb2,
    int N, int K) {
  constexpr int NJ = TN / 32;
  __shared__ bf16 As[128 * 32];
  __shared__ bf16 Bs[TN * 32];
  int bn = blockIdx.x * TN, bm = blockIdx.y * 128;
  int tid = threadIdx.x, lane = tid & 63, w = tid >> 6;
  int lo = lane & 15, hi = lane >> 4;
  int wr = (w >> 1) * 64, wc = (w & 1) * (TN / 2);
  f32x4 acc[4][NJ] = {};

  int srow = tid >> 2, sseg = tid & 3;
  const bf16* gA = A + (size_t)(bm + srow) * K + sseg * 8;
  const bf16* gB = W + (size_t)(bn + srow) * K + sseg * 8;
  bf16* lA = As + srow * 32 + sseg * 8;
  bf16* lB = Bs + srow * 32 + sseg * 8;

  for (int k0 = 0; k0 < K; k0 += 32) {
    load_lds16(gA + k0, lA);
    load_lds16(gA + (size_t)64 * K + k0, lA + 64 * 32);
    load_lds16(gB + k0, lB);
    if constexpr (TN == 128) load_lds16(gB + (size_t)64 * K + k0, lB + 64 * 32);
    __syncthreads();
    s16x8 af[4], bfr[NJ];
#pragma unroll
    for (int mi = 0; mi < 4; mi++) af[mi] = *(const s16x8*)(As + (wr + mi * 16 + lo) * 32 + hi * 8);
#pragma unroll
    for (int nj = 0; nj < NJ; nj++) bfr[nj] = *(const s16x8*)(Bs + (wc + nj * 16 + lo) * 32 + hi * 8);
#pragma unroll
    for (int mi = 0; mi < 4; mi++)
#pragma unroll
      for (int nj = 0; nj < NJ; nj++)
        acc[mi][nj] = __builtin_amdgcn_mfma_f32_16x16x32_bf16(af[mi], bfr[nj], acc[mi][nj], 0, 0, 0);
    __syncthreads();
  }

#pragma unroll
  for (int mi = 0; mi < 4; mi++)
#pragma unroll
    for (int nj = 0; nj < NJ; nj++)
#pragma unroll
      for (int r = 0; r < 4; r++) {
        int m = bm + wr + mi * 16 + hi * 4 + r;
        int n = bn + wc + nj * 16 + lo;
        float v = acc[mi][nj][r];
        if constexpr (EPI == 0) {
          int which = n >> 10;           // uniform per block (tiles never straddle)
          int d = n & 1023, h = d >> 6, dh = d & 63;
          int s = m >> 1, bb = m & 1;
          const float* bp = which == 0 ? b0p : (which == 1 ? b1p : b2p);
          v += bp[d];
          if (which < 2) {
            float pv = __shfl_xor(v, 1);
            float2 cn = rope2[s * 32 + (dh >> 1)];
            float o = (dh & 1) ? (v * cn.x + pv * cn.y) : (v * cn.x - pv * cn.y);
            bf16* dst = which == 0 ? Cb0 : Cb1;
            dst[(((size_t)(bb * NHEAD + h)) * S_LEN + s) * DHEAD + dh] = __float2bfloat16(o);
          } else {
            Cb2[(((size_t)(bb * NHEAD + h)) * DHEAD + dh) * S_LEN + s] = __float2bfloat16(v);
          }
        } else if constexpr (EPI == 1) {
          Cf[(size_t)m * N + n] = v + b0p[n];
        } else {
          Cb0[(size_t)m * N + n] = __float2bfloat16(fmaxf(v + b0p[n], 0.0f));
        }
      }
}

// ---------------- flash attention: swapped QK^T, lane-local softmax, no LDS ----------------
// Q,K: [bh][s][64] bf16 (rope'd). Vt: [bh][d][s] bf16. O: (s,b,D) bf16.
__global__ __launch_bounds__(256) void flash_attn(const bf16* __restrict__ Q,
    const bf16* __restrict__ K, const bf16* __restrict__ Vt, bf16* __restrict__ O) {
  int qt = (int)(gridDim.x - 1) - (int)blockIdx.x;   // big blocks first
  int bh = blockIdx.y;
  int b = bh >> 4, h = bh & 15;
  int w = threadIdx.x >> 6, lane = threadIdx.x & 63;
  int lo = lane & 15, hi = lane >> 4;
  const size_t qkb = (size_t)bh * S_LEN * DHEAD;
  const size_t vtb = (size_t)bh * DHEAD * S_LEN;
  int q0 = qt * 64 + w * 16;
  int qa = q0 + lo;
  const bf16* qp = Q + qkb + (size_t)(q0 + lo) * DHEAD + hi * 8;
  s16x8 bq0 = *(const s16x8*)qp;
  s16x8 bq1 = *(const s16x8*)(qp + 32);
  f32x4 accO[4] = {};
  float mv = -INFINITY, lv = 0.0f;
  int nkt = (q0 + 47) >> 5;
  for (int kt = 0; kt < nkt; kt++) {
    int kc = kt * 32;
    const bf16* kp = K + qkb + (size_t)(kc + lo) * DHEAD + hi * 8;
    s16x8 ka0 = *(const s16x8*)kp;
    s16x8 ka1 = *(const s16x8*)(kp + 32);
    s16x8 ka2 = *(const s16x8*)(kp + 16 * DHEAD);
    s16x8 ka3 = *(const s16x8*)(kp + 16 * DHEAD + 32);
    f32x4 st0 = {}, st1 = {};
    st0 = __builtin_amdgcn_mfma_f32_16x16x32_bf16(ka0, bq0, st0, 0, 0, 0);
    st0 = __builtin_amdgcn_mfma_f32_16x16x32_bf16(ka1, bq1, st0, 0, 0, 0);
    st1 = __builtin_amdgcn_mfma_f32_16x16x32_bf16(ka2, bq0, st1, 0, 0, 0);
    st1 = __builtin_amdgcn_mfma_f32_16x16x32_bf16(ka3, bq1, st1, 0, 0, 0);
    // S^T[k][q]: lane holds k = kc + hi*4 + r (+16), q = q0 + lo  -> per-q state lane-local
    float p[8], pmax = -INFINITY;
#pragma unroll
    for (int r = 0; r < 4; r++) {
      int k0a = kc + hi * 4 + r;
      float s0 = (k0a <= qa) ? st0[r] * 0.125f : -INFINITY;
      float s1 = (k0a + 16 <= qa) ? st1[r] * 0.125f : -INFINITY;
      p[r] = s0; p[4 + r] = s1;
      pmax = fmaxf(pmax, fmaxf(s0, s1));
    }
    pmax = fmaxf(pmax, __shfl_xor(pmax, 16));
    pmax = fmaxf(pmax, __shfl_xor(pmax, 32));
    float mnew = fmaxf(mv, pmax);
    float fs = __expf(mv - mnew);
    float sum = 0.0f;
#pragma unroll
    for (int j = 0; j < 8; j++) { p[j] = __expf(p[j] - mnew); sum += p[j]; }
    sum += __shfl_xor(sum, 16);
    sum += __shfl_xor(sum, 32);
    lv = lv * fs + sum;
    mv = mnew;
#pragma unroll
    for (int c = 0; c < 4; c++) accO[c] *= fs;
    // redistribute P -> PV B-frag: lane needs P[q=lo][k=hi*8..hi*8+7]
    unsigned u0 = pack2(p[0], p[1]), u1 = pack2(p[2], p[3]);
    unsigned u2 = pack2(p[4], p[5]), u3 = pack2(p[6], p[7]);
    int s1l = lo + ((hi & 1) << 5);
    int s2l = s1l + 16;
    unsigned a0 = (unsigned)__shfl((int)u0, s1l), a1 = (unsigned)__shfl((int)u1, s1l);
    unsigned a2 = (unsigned)__shfl((int)u0, s2l), a3 = (unsigned)__shfl((int)u1, s2l);
    unsigned c0 = (unsigned)__shfl((int)u2, s1l), c1 = (unsigned)__shfl((int)u3, s1l);
    unsigned c2 = (unsigned)__shfl((int)u2, s2l), c3 = (unsigned)__shfl((int)u3, s2l);
    bool lk = hi < 2;
    i32x4 pi;
    pi.x = (int)(lk ? a0 : c0); pi.y = (int)(lk ? a1 : c1);
    pi.z = (int)(lk ? a2 : c2); pi.w = (int)(lk ? a3 : c3);
    s16x8 pf = __builtin_bit_cast(s16x8, pi);
    const bf16* vp = Vt + vtb + (size_t)lo * S_LEN + kc + hi * 8;
#pragma unroll
    for (int c = 0; c < 4; c++) {
      s16x8 va = *(const s16x8*)(vp + (size_t)c * 16 * S_LEN);
      accO[c] = __builtin_amdgcn_mfma_f32_16x16x32_bf16(va, pf, accO[c], 0, 0, 0);
    }
  }
  float linv = 1.0f / lv;
#pragma unroll
  for (int c = 0; c < 4; c++) {
    ushort4 ov;
    ov.x = __builtin_bit_cast(unsigned short, __float2bfloat16(accO[c][0] * linv));
    ov.y = __builtin_bit_cast(unsigned short, __float2bfloat16(accO[c][1] * linv));
    ov.z = __builtin_bit_cast(unsigned short, __float2bfloat16(accO[c][2] * linv));
    ov.w = __builtin_bit_cast(unsigned short, __float2bfloat16(accO[c][3] * linv));
    *(ushort4*)(O + ((size_t)qa * BATCH + b) * DMOD + h * DHEAD + c * 16 + hi * 4) = ov;
  }
}

// ---------------- LayerNorm(a + r) * g + be -> outf/outb ----------------
__global__ __launch_bounds__(256) void ln_kernel(const float* __restrict__ a,
    const float* __restrict__ r, const float* __restrict__ g,
    const float* __restrict__ be, float* __restrict__ outf, bf16* __restrict__ outb) {
  int m = blockIdx.x;
  int tid = threadIdx.x;
  float vals[4];
  float s1 = 0.f, s2 = 0.f;
  for (int j = 0; j < 4; j++) {
    int d = tid + j * 256;
    float v = a[(size_t)m * DMOD + d] + r[(size_t)m * DMOD + d];
    vals[j] = v; s1 += v; s2 += v * v;
  }
  __shared__ float red[8];
  for (int d = 1; d < 64; d <<= 1) { s1 += __shfl_xor(s1, d); s2 += __shfl_xor(s2, d); }
  int w = tid >> 6, lane = tid & 63;
  if (lane == 0) { red[w] = s1; red[4 + w] = s2; }
  __syncthreads();
  s1 = red[0] + red[1] + red[2] + red[3];
  s2 = red[4] + red[5] + red[6] + red[7];
  float mean = s1 * (1.0f / DMOD);
  float var = s2 * (1.0f / DMOD) - mean * mean;
  float rstd = rsqrtf(var + 1e-5f);
  for (int j = 0; j < 4; j++) {
    int d = tid + j * 256;
    float o = (vals[j] - mean) * rstd * g[d] + be[d];
    outf[(size_t)m * DMOD + d] = o;
    outb[(size_t)m * DMOD + d] = __float2bfloat16(o);
  }
}

// ---------------- head ----------------
__global__ __launch_bounds__(256) void head_kernel(const float* __restrict__ x,
    const float* __restrict__ Wh, const float* __restrict__ bh, float* __restrict__ out) {
  int m = blockIdx.x * 4 + (threadIdx.x >> 6);
  int lane = threadIdx.x & 63;
  float s = 0.f;
  for (int j = 0; j < 16; j++) {
    int d = lane + j * 64;
    s += x[(size_t)m * DMOD + d] * Wh[d];
  }
  for (int d = 1; d < 64; d <<= 1) s += __shfl_xor(s, d);
  if (lane == 0) out[m] = s + bh[0];
}

extern "C" void kernel_launch(void* const* d_in, const int* in_sizes, int n_in,
                              void* d_out, int out_size, void* d_ws, size_t ws_size,
                              hipStream_t stream) {
  (void)in_sizes; (void)n_in; (void)out_size; (void)ws_size;
  const float* tokens = (const float*)d_in[0];
  const float* Win    = (const float*)d_in[1];
  const float* binp   = (const float*)d_in[2];
  const float* pos    = (const float*)d_in[3];
  const float* Wq     = (const float*)d_in[4];
  const float* bq     = (const float*)d_in[5];
  const float* Wk     = (const float*)d_in[6];
  const float* bk     = (const float*)d_in[7];
  const float* Wv     = (const float*)d_in[8];
  const float* bv     = (const float*)d_in[9];
  const float* Wo     = (const float*)d_in[10];
  const float* bo     = (const float*)d_in[11];
  const float* W1     = (const float*)d_in[12];
  const float* b1     = (const float*)d_in[13];
  const float* W2     = (const float*)d_in[14];
  const float* b2     = (const float*)d_in[15];
  const float* g1     = (const float*)d_in[16];
  const float* be1    = (const float*)d_in[17];
  const float* g2     = (const float*)d_in[18];
  const float* be2    = (const float*)d_in[19];
  const float* Wh     = (const float*)d_in[20];
  const float* bhp    = (const float*)d_in[21];
  float* out = (float*)d_out;

  char* p = (char*)d_ws;
  auto alloc = [&](size_t bytes) { char* r = p; p += (bytes + 255) & ~(size_t)255; return r; };
  float* xf   = (float*)alloc((size_t)MROWS * DMOD * 4);
  bf16*  xb   = (bf16*) alloc((size_t)MROWS * DMOD * 2);
  float* x2f  = (float*)alloc((size_t)MROWS * DMOD * 4);
  bf16*  x2b  = (bf16*) alloc((size_t)MROWS * DMOD * 2);
  float* tmpf = (float*)alloc((size_t)MROWS * DMOD * 4);
  bf16*  qb   = (bf16*) alloc((size_t)MROWS * DMOD * 2);
  bf16*  kb   = (bf16*) alloc((size_t)MROWS * DMOD * 2);
  bf16*  vt   = (bf16*) alloc((size_t)MROWS * DMOD * 2);
  bf16*  ob   = (bf16*) alloc((size_t)MROWS * DMOD * 2);
  bf16*  hb   = (bf16*) alloc((size_t)MROWS * FDIM * 2);
  bf16*  wb   = (bf16*) alloc((4 * DD_ + 2 * FD_) * 2);   // 16 MB per-layer weights
  float* WinT = (float*)alloc((size_t)TDIM * DMOD * 4);
  float2* rope2 = (float2*)alloc((size_t)S_LEN * 32 * 8);

  transpose_win<<<(TDIM * DMOD + 255) / 256, 256, 0, stream>>>(Win, WinT);
  rope_table<<<(S_LEN * 32 + 255) / 256, 256, 0, stream>>>(rope2);
  embed_kernel<<<dim3(MROWS, 4), 256, 0, stream>>>(tokens, WinT, binp, pos, xf, xb);

  const int nW4 = (int)((4 * DD_ + 2 * FD_) / 4);

  for (int l = 0; l < NLAYER; l++) {
    f2b_layer<<<(nW4 + 255) / 256, 256, 0, stream>>>(
        (const float4*)(Wq + l * DD_), (const float4*)(Wk + l * DD_),
        (const float4*)(Wv + l * DD_), (const float4*)(Wo + l * DD_),
        (const float4*)(W1 + l * FD_), (const float4*)(W2 + l * FD_), (ushort4*)wb);

    // fused QKV GEMM (N=3072) with rope + head-layout + V^T epilogue
    gemm128<128, 0><<<dim3(3 * DMOD / 128, MROWS / 128), 256, 0, stream>>>(
        xb, wb, bq + l * DMOD, bk + l * DMOD, bv + l * DMOD, rope2,
        nullptr, qb, kb, vt, 3 * DMOD, DMOD);

    flash_attn<<<dim3(S_LEN / 64, BATCH * NHEAD), 256, 0, stream>>>(qb, kb, vt, ob);

    gemm128<64, 1><<<dim3(DMOD / 64, MROWS / 128), 256, 0, stream>>>(
        ob, wb + 3 * DD_, bo + l * DMOD, nullptr, nullptr, nullptr,
        tmpf, nullptr, nullptr, nullptr, DMOD, DMOD);

    ln_kernel<<<MROWS, 256, 0, stream>>>(xf, tmpf, g1 + l * DMOD, be1 + l * DMOD, x2f, x2b);

    gemm128<128, 2><<<dim3(FDIM / 128, MROWS / 128), 256, 0, stream>>>(
        x2b, wb + 4 * DD_, b1 + l * FDIM, nullptr, nullptr, nullptr,
        nullptr, hb, nullptr, nullptr, FDIM, DMOD);

    gemm128<64, 1><<<dim3(DMOD / 64, MROWS / 128), 256, 0, stream>>>(
        hb, wb + 4 * DD_ + FD_, b2 + l * DMOD, nullptr, nullptr, nullptr,
        tmpf, nullptr, nullptr, nullptr, DMOD, FDIM);

    ln_kernel<<<MROWS, 256, 0, stream>>>(x2f, tmpf, g2 + l * DMOD, be2 + l * DMOD, xf, xb);
  }

  head_kernel<<<MROWS / 4, 256, 0, stream>>>(xf, Wh, bhp, out);
}